// Round 5
// baseline (926.570 us; speedup 1.0000x reference)
//
#include <hip/hip_runtime.h>
#include <stdint.h>
#include <stddef.h>

// Problem constants (fixed by the reference)
#define M_ROWS 32768      // B*N = 16*2048
#define N_CODES 8192
#define K_DIM 512
#define BM 128
#define BN 128
#define BK 64
#define KTILES (K_DIM / BK)     // 8 K-tiles, 2 per pipeline iteration
#define CAND_CAP (3u*1024u*1024u)
#define LCAP 512u               // per-block LDS candidate slab
#define TAU2 2.0f               // 2*tau admission margin for bf16 approx distances (>10 sigma)

// Output layout (floats): z_q [0,16777216), codes [16777216,16809984), loss, perp
#define OFF_CODES 16777216
#define OFF_LOSS  (16777216 + 32768)
#define OFF_PERP  (16777216 + 32768 + 1)

using short8  = __attribute__((ext_vector_type(8))) short;
using ushort8 = __attribute__((ext_vector_type(8))) unsigned short;
using f32x4   = __attribute__((ext_vector_type(4))) float;

typedef unsigned short u16;
typedef unsigned int   u32;
typedef unsigned long long u64;

// ---- orderable-uint encoding of float (monotone: uint min == float min) ----
__device__ __forceinline__ u32 ford(float f) {
    u32 u = __float_as_uint(f);
    return (u & 0x80000000u) ? ~u : (u | 0x80000000u);
}
__device__ __forceinline__ float fordinv(u32 u) {
    u32 v = (u & 0x80000000u) ? (u & 0x7FFFFFFFu) : ~u;
    return __uint_as_float(v);
}
// fp32 -> bf16 (RNE)
__device__ __forceinline__ u16 f2bf(float f) {
    u32 u = __float_as_uint(f);
    u = u + 0x7FFFu + ((u >> 16) & 1u);
    return (u16)(u >> 16);
}

// async global->LDS, 16B per lane; LDS dest = wave-uniform base + lane*16
__device__ __forceinline__ void ldg_to_lds16(const u16* g, u16* l) {
    __builtin_amdgcn_global_load_lds((__attribute__((address_space(1))) void*)(g),
                                     (__attribute__((address_space(3))) void*)(l),
                                     16, 0, 0);
}
// generic (__shared__) pointer -> 32-bit LDS byte address for asm ds ops
__device__ __forceinline__ u32 lds_addr(const void* p) {
    return (u32)(uintptr_t)(__attribute__((address_space(3))) const void*)p;
}

// ---------------- init scratch state ----------------
__global__ void k_init(u32* rowMin, u64* rowBest, u32* counts, u32* candCnt) {
    int i = blockIdx.x * blockDim.x + threadIdx.x;
    if (i < M_ROWS) { rowMin[i] = 0xFFFFFFFFu; rowBest[i] = ~0ull; }
    if (i < N_CODES) counts[i] = 0u;
    if (i == 0) *candCnt = 0u;
}

// ------------- fp32 -> bf16 convert + row squared norms -------------
__global__ void k_convert(const float* __restrict__ src, u16* __restrict__ dst,
                          float* __restrict__ nrm2, int nrows) {
    int row  = blockIdx.x * 4 + (threadIdx.x >> 6);
    int lane = threadIdx.x & 63;
    if (row >= nrows) return;
    const float* p = src + (size_t)row * K_DIM + lane * 8;
    float4 a = *(const float4*)p;
    float4 b = *(const float4*)(p + 4);
    ushort8 v;
    v[0]=f2bf(a.x); v[1]=f2bf(a.y); v[2]=f2bf(a.z); v[3]=f2bf(a.w);
    v[4]=f2bf(b.x); v[5]=f2bf(b.y); v[6]=f2bf(b.z); v[7]=f2bf(b.w);
    *(ushort8*)(dst + (size_t)row * K_DIM + lane * 8) = v;
    float ss = a.x*a.x + a.y*a.y + a.z*a.z + a.w*a.w
             + b.x*b.x + b.y*b.y + b.z*b.z + b.w*b.w;
    #pragma unroll
    for (int s = 32; s; s >>= 1) ss += __shfl_xor(ss, s);
    if (lane == 0) nrm2[row] = ss;
}

// ---------------- main bf16 GEMM + fused min/candidate epilogue ----------------
// R5: 128x128 tile, 4 waves (2x2), BK=64, SAME 8-phase/counted-vmcnt pipeline
// as R2-R4 but with LDS cut to ~69 KiB -> 2 blocks/CU. R4 counters showed the
// 256x256 1-block/CU version latency-stalls every phase with nothing to
// overlap (MfmaUtil 19%, VALU 16%, HBM 6.6%, conflicts 0). Cross-block wave
// overlap (the mechanism that let the old m97-style kernel hit ~600 TF with
// no pipelining at all) now covers per-block stalls; setprio(1) favors the
// MFMA-entering waves.
//
// LDS ring: [buf2][mat2][half2][4096 u16] = 64 KiB. Half-slab = 128 rows x
// 32 cols as 512 x 16B blocks; block(R,q) at slot (R>>3)*32 + q*8 + (R&7);
// staging block index b == slot identically -> lane-linear DMA dest,
// conflict-free ds_read_b128 reads.
//
// Phase map (iter: tile t=2i in buf0, u=t+1 in buf1; one half-slab staged
// per phase; MFMA quad = n-pair p of the current (buf,h); af persists from
// the h-opening phase):
//   ph1: rdA(0,0)+rdB(0,0,0) | stage b1.A.h1(u)    ph5: rdA(1,0)+rdB(1,0,0) | stage b0.A.h1(t+2)
//   ph2: rdB(0,0,1)          | stage b1.B.h1(u)    ph6: rdB(1,0,1)          | stage b0.B.h1(t+2)
//   ph3: rdA(0,1)+rdB(0,1,0) | stage b0.A.h0(t+2)  ph7: rdA(1,1)+rdB(1,1,0) | stage b1.A.h0(t+3)
//   ph4: rdB(0,1,1)          | stage b0.B.h0(t+2)  ph8: rdB(1,1,1)          | stage b1.B.h0(t+3)
// vmcnt(4) ONLY at ph4/ph8 (retires the 8 oldest = everything read in the
// next 1-4 phases; leaves newest 2 half-slabs in flight). Tail peeled:
// ph1/ph2 stage buf1.h1(7); VMW4@ph4 retires buf1.h0(7), VMW0@ph6 the rest.
// K-slices ascending -> numerics identical to all prior passing versions.
__global__ __launch_bounds__(256, 2)
void k_gemm(const u16* __restrict__ zb, const u16* __restrict__ eb,
            const float* __restrict__ en2, u32* __restrict__ rowMin,
            u32* __restrict__ candCnt, u64* __restrict__ cand) {
    __shared__ __align__(16) u16 lds[32768];   // 64 KiB ring
    __shared__ float en2s[BN];
    __shared__ u32 threshL[BM];
    __shared__ u64 candBuf[LCAP];
    __shared__ u32 ldsCnt, ldsBase;

    const int tid  = threadIdx.x;
    const int lane = tid & 63;
    const int wave = tid >> 6;          // 0..3
    const int wr   = wave >> 1;         // row half (64 rows per wave)
    const int wc   = (wave & 1) * 64;   // col half base (64 cols per wave)
    const int rowTile = blockIdx.x * BM;
    const int nTile   = blockIdx.y * BN;

    if (tid < BN) en2s[tid] = en2[nTile + tid];
    if (tid < BM) threshL[tid] = 0xFFFFFFFFu;
    if (tid == 0) ldsCnt = 0u;

    // --- staging: 16B block b; G=b>>5, q=(b>>3)&3, r=b&7 -> global row G*8+r,
    //     u16 cols q*8..+8 of the 32-col half. b0 = wave*64+lane, b1 = 256+b0.
    const u16* zbp = zb + (size_t)rowTile * K_DIM;
    const u16* ebp = eb + (size_t)nTile * K_DIM;
    int b0 = wave*64 + lane;
    int b1 = 256 + wave*64 + lane;
    const size_t gOff0 = (size_t)((b0 >> 5)*8 + (b0 & 7)) * K_DIM + ((b0 >> 3) & 3)*8;
    const size_t gOff1 = (size_t)((b1 >> 5)*8 + (b1 & 7)) * K_DIM + ((b1 >> 3) & 3)*8;
    const int lOff0 = (wave*64) * 8;           // u16 units (block*8)
    const int lOff1 = (256 + wave*64) * 8;

    // --- fragment read LDS byte addresses
    // frag row R = M0 + (lane&15), q = lane>>4; byte = M0*64 + laneFB
    const int laneFB = ((lane >> 3) & 1)*512 + (lane >> 4)*128 + (lane & 7)*16;
    const u32 ldsB0 = lds_addr(lds);
    const u32 aAddr0 = ldsB0 + (u32)(wr*4096 + laneFB);            // + buf*32768 + h*8192 + mf*1024
    const u32 bAddr0 = ldsB0 + 16384u + (u32)((wave & 1)*4096 + laneFB); // + buf*32768 + h*8192 + p*2048

#define STAGE(buf, matB, h, tileIdx) do {                                     \
    int ko_ = (tileIdx) * BK + (h) * 32;                                      \
    const u16* g_ = (matB) ? ebp : zbp;                                       \
    u16* l_ = lds + (buf)*16384 + (matB)*8192 + (h)*4096;                     \
    ldg_to_lds16(g_ + gOff0 + ko_, l_ + lOff0);                               \
    ldg_to_lds16(g_ + gOff1 + ko_, l_ + lOff1);                               \
} while (0)

#define DSR(dst, a, IMM) asm volatile("ds_read_b128 %0, %1 offset:" #IMM      \
                                      : "=v"(dst) : "v"(a))

#define RD_A(buf, h) do {                                                     \
    u32 a_ = aAddr0 + (u32)((buf)*32768 + (h)*8192);                          \
    DSR(af[0], a_, 0);    DSR(af[1], a_, 1024);                               \
    DSR(af[2], a_, 2048); DSR(af[3], a_, 3072);                               \
} while (0)

#define RD_B(buf, h, p) do {                                                  \
    u32 b_ = bAddr0 + (u32)((buf)*32768 + (h)*8192 + (p)*2048);               \
    DSR(bf[0], b_, 0);    DSR(bf[1], b_, 1024);                               \
} while (0)

#define BARF() do { asm volatile("" ::: "memory");                            \
    __builtin_amdgcn_s_barrier(); asm volatile("" ::: "memory"); } while (0)
#define VMW4() asm volatile("s_waitcnt vmcnt(4)" ::: "memory")
#define VMW0() asm volatile("s_waitcnt vmcnt(0)" ::: "memory")
// rule #18: lgkmcnt wait + hard scheduling fence so MFMAs can't hoist above it
#define LGKM0() do { asm volatile("s_waitcnt lgkmcnt(0)" ::: "memory");       \
                     __builtin_amdgcn_sched_barrier(0); } while (0)

#define MFMA_P(p) do {                                                        \
    __builtin_amdgcn_s_setprio(1);                                            \
    _Pragma("unroll") for (int m_ = 0; m_ < 4; m_++)                          \
      _Pragma("unroll") for (int n_ = 0; n_ < 2; n_++)                        \
        acc[m_][(p)*2 + n_] = __builtin_amdgcn_mfma_f32_16x16x32_bf16(        \
            af[m_], bf[n_], acc[m_][(p)*2 + n_], 0, 0, 0);                    \
    __builtin_amdgcn_s_setprio(0);                                            \
} while (0)

    f32x4 acc[4][4] = {};
    short8 af[4], bf[2];

    // prologue: tile0 fully + tile1 h0; vmcnt(4) -> tile0's 4 half-slabs landed
    STAGE(0,0,0,0); STAGE(0,1,0,0); STAGE(0,0,1,0); STAGE(0,1,1,0);
    STAGE(1,0,0,1); STAGE(1,1,0,1);
    VMW4();
    BARF();

    for (int i = 0; i < KTILES/2 - 1; i++) {   // iterations 0..2 (tiles 0..5)
        const int t = 2*i, u = t + 1;
        RD_A(0,0); RD_B(0,0,0); STAGE(1,0,1,u);          // ph1
        BARF(); LGKM0(); MFMA_P(0); BARF();
        RD_B(0,0,1); STAGE(1,1,1,u);                     // ph2
        BARF(); LGKM0(); MFMA_P(1); BARF();
        RD_A(0,1); RD_B(0,1,0); STAGE(0,0,0,t+2);        // ph3
        BARF(); LGKM0(); MFMA_P(0); BARF();
        RD_B(0,1,1); STAGE(0,1,0,t+2); VMW4();           // ph4
        BARF(); LGKM0(); MFMA_P(1); BARF();
        RD_A(1,0); RD_B(1,0,0); STAGE(0,0,1,t+2);        // ph5
        BARF(); LGKM0(); MFMA_P(0); BARF();
        RD_B(1,0,1); STAGE(0,1,1,t+2);                   // ph6
        BARF(); LGKM0(); MFMA_P(1); BARF();
        RD_A(1,1); RD_B(1,1,0); STAGE(1,0,0,t+3);        // ph7
        BARF(); LGKM0(); MFMA_P(0); BARF();
        RD_B(1,1,1); STAGE(1,1,0,t+3); VMW4();           // ph8
        BARF(); LGKM0(); MFMA_P(1); BARF();
    }
    {   // peeled tail: tiles 6 (buf0) and 7 (buf1); only ph1/ph2 stage.
        RD_A(0,0); RD_B(0,0,0); STAGE(1,0,1,7);          // ph1: stage buf1.A.h1(7)
        BARF(); LGKM0(); MFMA_P(0); BARF();
        RD_B(0,0,1); STAGE(1,1,1,7);                     // ph2: stage buf1.B.h1(7)
        BARF(); LGKM0(); MFMA_P(1); BARF();
        RD_A(0,1); RD_B(0,1,0);                          // ph3
        BARF(); LGKM0(); MFMA_P(0); BARF();
        RD_B(0,1,1); VMW4();                             // ph4: retires buf1.h0(7)
        BARF(); LGKM0(); MFMA_P(1); BARF();
        RD_A(1,0); RD_B(1,0,0);                          // ph5
        BARF(); LGKM0(); MFMA_P(0); BARF();
        RD_B(1,0,1); VMW0();                             // ph6: retires buf1.h1(7)
        BARF(); LGKM0(); MFMA_P(1); BARF();
        RD_A(1,1); RD_B(1,1,0);                          // ph7
        BARF(); LGKM0(); MFMA_P(0); BARF();
        RD_B(1,1,1);                                     // ph8
        BARF(); LGKM0(); MFMA_P(1); BARF();
    }

    // ---- epilogue: s = en2 - 2*C ; per-row tile min ; candidate capture ----
    // C/D layout (16x16x32): col = lane&15, row = (lane>>4)*4 + reg
    float e2v[4];
    #pragma unroll
    for (int n = 0; n < 4; n++) e2v[n] = en2s[wc + n*16 + (lane & 15)];
    #pragma unroll
    for (int m = 0; m < 4; m++)
        #pragma unroll
        for (int n = 0; n < 4; n++)
            #pragma unroll
            for (int r = 0; r < 4; r++)
                acc[m][n][r] = e2v[n] - 2.0f * acc[m][n][r];

    float rm[4][4];
    #pragma unroll
    for (int m = 0; m < 4; m++)
        #pragma unroll
        for (int r = 0; r < 4; r++)
            rm[m][r] = fminf(fminf(acc[m][0][r], acc[m][1][r]),
                             fminf(acc[m][2][r], acc[m][3][r]));
    #pragma unroll
    for (int d = 1; d < 16; d <<= 1)
        #pragma unroll
        for (int m = 0; m < 4; m++)
            #pragma unroll
            for (int r = 0; r < 4; r++)
                rm[m][r] = fminf(rm[m][r], __shfl_xor(rm[m][r], d));

    const int q4 = lane >> 4;
    if ((lane & 15) == 0) {
        #pragma unroll
        for (int m = 0; m < 4; m++)
            #pragma unroll
            for (int r = 0; r < 4; r++) {
                int lrow = wr*64 + m*16 + q4*4 + r;
                u32 o = ford(rm[m][r]);
                atomicMin(&threshL[lrow], o);
                u32 old = atomicMin(&rowMin[rowTile + lrow], o);  // tighten via earlier tiles
                atomicMin(&threshL[lrow], old);
            }
    }
    __syncthreads();

    #pragma unroll
    for (int m = 0; m < 4; m++) {
        #pragma unroll
        for (int r = 0; r < 4; r++) {
            int lrow = wr*64 + m*16 + q4*4 + r;
            float th = fordinv(threshL[lrow]) + TAU2;
            #pragma unroll
            for (int n = 0; n < 4; n++) {
                float sv = acc[m][n][r];
                if (sv <= th) {
                    u32 code = (u32)(nTile + wc + n*16 + (lane & 15));
                    u64 pk = ((u64)ford(sv) << 32) |
                             (u64)(((u32)(rowTile + lrow) << 13) | code);
                    u32 idx = atomicAdd(&ldsCnt, 1u);       // LDS atomic: cheap
                    if (idx < LCAP) candBuf[idx] = pk;
                    else { u32 g = atomicAdd(candCnt, 1u);  // rare overflow path
                           if (g < CAND_CAP) cand[g] = pk; }
                }
            }
        }
    }
    __syncthreads();
    if (tid == 0) {
        u32 n = ldsCnt < LCAP ? ldsCnt : LCAP;
        ldsBase = atomicAdd(candCnt, n);                    // ONE global atomic per block
    }
    __syncthreads();
    u32 nn = ldsCnt < LCAP ? ldsCnt : LCAP;
    for (u32 k2 = tid; k2 < nn; k2 += 256) {
        u32 g = ldsBase + k2;
        if (g < CAND_CAP) cand[g] = candBuf[k2];
    }
#undef STAGE
#undef DSR
#undef RD_A
#undef RD_B
#undef BARF
#undef VMW4
#undef VMW0
#undef LGKM0
#undef MFMA_P
}

// ---------------- fp32 exact refine of pruned candidates ----------------
__global__ void k_refine(const float* __restrict__ z, const float* __restrict__ emb,
                         const float* __restrict__ en2, const u32* __restrict__ candCnt,
                         const u64* __restrict__ cand, const u32* __restrict__ rowMin,
                         u64* __restrict__ rowBest) {
    u32 cnt = *candCnt; if (cnt > CAND_CAP) cnt = CAND_CAP;
    int gt = blockIdx.x * blockDim.x + threadIdx.x;
    u32 wid = (u32)(gt >> 6);
    int lane = gt & 63;
    u32 nw = (u32)((gridDim.x * blockDim.x) >> 6);
    for (u32 ci = wid; ci < cnt; ci += nw) {
        u64 pk = cand[ci];
        u32 rc = (u32)pk;
        u32 row = rc >> 13, code = rc & (N_CODES - 1);
        float ad = fordinv((u32)(pk >> 32));
        float gm = fordinv(rowMin[row]);
        if (ad > gm + TAU2) continue;   // pruned: can't be the true argmin
        const float4* zp = (const float4*)(z + (size_t)row * K_DIM) + lane * 2;
        const float4* ep = (const float4*)(emb + (size_t)code * K_DIM) + lane * 2;
        float4 a0 = zp[0], a1 = zp[1], b0 = ep[0], b1 = ep[1];
        float d = a0.x*b0.x + a0.y*b0.y + a0.z*b0.z + a0.w*b0.w
                + a1.x*b1.x + a1.y*b1.y + a1.z*b1.z + a1.w*b1.w;
        #pragma unroll
        for (int s = 32; s; s >>= 1) d += __shfl_xor(d, s);
        if (lane == 0) {
            float sv = en2[code] - 2.0f * d;
            u64 bk = ((u64)ford(sv) << 32) | (u64)code;
            atomicMin(rowBest + row, bk);
        }
    }
}

// ---------------- outputs: z_q gather, codes, counts ----------------
__global__ void k_output(const u64* __restrict__ rowBest, const float* __restrict__ emb,
                         float* __restrict__ out, u32* __restrict__ counts) {
    int row = blockIdx.x;
    u64 pk = rowBest[row];
    u32 code = (u32)(pk & 0xFFFFFFFFull);
    int t = threadIdx.x;  // 128 threads, 4 floats each
    float4 v = ((const float4*)(emb + (size_t)code * K_DIM))[t];
    ((float4*)(out + (size_t)row * K_DIM))[t] = v;
    if (t == 0) {
        out[OFF_CODES + row] = (float)code;
        atomicAdd(&counts[code], 1u);
    }
}

// ---------------- loss + perplexity ----------------
__global__ void k_final(const u64* __restrict__ rowBest, const float* __restrict__ zn2,
                        const u32* __restrict__ counts, float* __restrict__ out) {
    __shared__ float red[256];
    int t = threadIdx.x;
    float s1 = 0.f;
    for (int r = t; r < M_ROWS; r += 256)
        s1 += zn2[r] + fordinv((u32)(rowBest[r] >> 32));
    red[t] = s1; __syncthreads();
    for (int w = 128; w; w >>= 1) { if (t < w) red[t] += red[t + w]; __syncthreads(); }
    float lossSum = red[0];
    __syncthreads();
    float s2 = 0.f;
    for (int c = t; c < N_CODES; c += 256) {
        float p = (float)counts[c] * (1.0f / (float)M_ROWS);
        s2 += p * logf(p + 1e-10f);
    }
    red[t] = s2; __syncthreads();
    for (int w = 128; w; w >>= 1) { if (t < w) red[t] += red[t + w]; __syncthreads(); }
    if (t == 0) {
        out[OFF_LOSS] = 0.25f * lossSum / ((float)M_ROWS * (float)K_DIM);
        out[OFF_PERP] = expf(-red[0]);
    }
}

// ---------------- workspace layout (bytes) ----------------
#define WS_ZB      ((size_t)0)                       // 32768*512*2  = 33554432
#define WS_EB      ((size_t)33554432)                // 8192*512*2   = 8388608
#define WS_EN2     ((size_t)41943040)                // 8192*4
#define WS_ZN2     ((size_t)41975808)                // 32768*4
#define WS_ROWMIN  ((size_t)42106880)                // 32768*4
#define WS_ROWBEST ((size_t)42237952)                // 32768*8
#define WS_COUNTS  ((size_t)42500096)                // 8192*4
#define WS_CANDCNT ((size_t)42532864)                // 256
#define WS_CAND    ((size_t)42533120)                // 3M*8 = 25165824 -> total ~67.7MB

extern "C" void kernel_launch(void* const* d_in, const int* in_sizes, int n_in,
                              void* d_out, int out_size, void* d_ws, size_t ws_size,
                              hipStream_t stream) {
    const float* z   = (const float*)d_in[0];
    const float* emb = (const float*)d_in[1];
    float* out = (float*)d_out;
    char* ws = (char*)d_ws;

    u16*  zb      = (u16*)(ws + WS_ZB);
    u16*  eb      = (u16*)(ws + WS_EB);
    float* en2    = (float*)(ws + WS_EN2);
    float* zn2    = (float*)(ws + WS_ZN2);
    u32*  rowMin  = (u32*)(ws + WS_ROWMIN);
    u64*  rowBest = (u64*)(ws + WS_ROWBEST);
    u32*  counts  = (u32*)(ws + WS_COUNTS);
    u32*  candCnt = (u32*)(ws + WS_CANDCNT);
    u64*  cand    = (u64*)(ws + WS_CAND);

    k_init<<<dim3(M_ROWS / 256), dim3(256), 0, stream>>>(rowMin, rowBest, counts, candCnt);
    k_convert<<<dim3(M_ROWS / 4), dim3(256), 0, stream>>>(z, zb, zn2, M_ROWS);
    k_convert<<<dim3(N_CODES / 4), dim3(256), 0, stream>>>(emb, eb, en2, N_CODES);
    k_gemm<<<dim3(M_ROWS / BM, N_CODES / BN), dim3(256), 0, stream>>>(zb, eb, en2, rowMin, candCnt, cand);
    k_refine<<<dim3(1024), dim3(256), 0, stream>>>(z, emb, en2, candCnt, cand, rowMin, rowBest);
    k_output<<<dim3(M_ROWS), dim3(128), 0, stream>>>(rowBest, emb, out, counts);
    k_final<<<dim3(1), dim3(256), 0, stream>>>(rowBest, zn2, counts, out);
}

// Round 6
// 647.701 us; speedup vs baseline: 1.4306x; 1.4306x over previous
//
#include <hip/hip_runtime.h>
#include <stdint.h>
#include <stddef.h>

// Problem constants (fixed by the reference)
#define M_ROWS 32768      // B*N = 16*2048
#define N_CODES 8192
#define K_DIM 512
#define BM 128
#define BN 128
#define BK 64
#define KITERS (K_DIM / BK)     // 8
#define CAND_CAP (3u*1024u*1024u)
#define LCAP 512u               // per-block LDS candidate slab
#define TAU2 2.0f               // 2*tau admission margin for bf16 approx distances (>10 sigma)

// Output layout (floats): z_q [0,16777216), codes [16777216,16809984), loss, perp
#define OFF_CODES 16777216
#define OFF_LOSS  (16777216 + 32768)
#define OFF_PERP  (16777216 + 32768 + 1)

using short8  = __attribute__((ext_vector_type(8))) short;
using ushort8 = __attribute__((ext_vector_type(8))) unsigned short;
using f32x4   = __attribute__((ext_vector_type(4))) float;

typedef unsigned short u16;
typedef unsigned int   u32;
typedef unsigned long long u64;

// ---- orderable-uint encoding of float (monotone: uint min == float min) ----
__device__ __forceinline__ u32 ford(float f) {
    u32 u = __float_as_uint(f);
    return (u & 0x80000000u) ? ~u : (u | 0x80000000u);
}
__device__ __forceinline__ float fordinv(u32 u) {
    u32 v = (u & 0x80000000u) ? (u & 0x7FFFFFFFu) : ~u;
    return __uint_as_float(v);
}
// fp32 -> bf16 (RNE)
__device__ __forceinline__ u16 f2bf(float f) {
    u32 u = __float_as_uint(f);
    u = u + 0x7FFFu + ((u >> 16) & 1u);
    return (u16)(u >> 16);
}

// async global->LDS, 16B per lane; LDS dest = wave-uniform base + lane*16
__device__ __forceinline__ void ldg_to_lds16(const u16* g, u16* l) {
    __builtin_amdgcn_global_load_lds((__attribute__((address_space(1))) void*)(g),
                                     (__attribute__((address_space(3))) void*)(l),
                                     16, 0, 0);
}

// ---------------- init scratch state ----------------
__global__ void k_init(u32* rowMin, u64* rowBest, u32* counts, u32* candCnt) {
    int i = blockIdx.x * blockDim.x + threadIdx.x;
    if (i < M_ROWS) { rowMin[i] = 0xFFFFFFFFu; rowBest[i] = ~0ull; }
    if (i < N_CODES) counts[i] = 0u;
    if (i == 0) *candCnt = 0u;
}

// ------------- fp32 -> bf16 convert + row squared norms -------------
__global__ void k_convert(const float* __restrict__ src, u16* __restrict__ dst,
                          float* __restrict__ nrm2, int nrows) {
    int row  = blockIdx.x * 4 + (threadIdx.x >> 6);
    int lane = threadIdx.x & 63;
    if (row >= nrows) return;
    const float* p = src + (size_t)row * K_DIM + lane * 8;
    float4 a = *(const float4*)p;
    float4 b = *(const float4*)(p + 4);
    ushort8 v;
    v[0]=f2bf(a.x); v[1]=f2bf(a.y); v[2]=f2bf(a.z); v[3]=f2bf(a.w);
    v[4]=f2bf(b.x); v[5]=f2bf(b.y); v[6]=f2bf(b.z); v[7]=f2bf(b.w);
    *(ushort8*)(dst + (size_t)row * K_DIM + lane * 8) = v;
    float ss = a.x*a.x + a.y*a.y + a.z*a.z + a.w*a.w
             + b.x*b.x + b.y*b.y + b.z*b.z + b.w*b.w;
    #pragma unroll
    for (int s = 32; s; s >>= 1) ss += __shfl_xor(ss, s);
    if (lane == 0) nrm2[row] = ss;
}

// ---------------- main bf16 GEMM + fused min/candidate epilogue ----------------
// REVERT (R6): session-start baseline structure, verbatim. Evidence from R2-R5:
// all fine-grained 8-phase/counted-vmcnt variants land at MfmaUtil 15-19%
// (621-742us) regardless of tile size or wave count -- the per-phase barrier
// rendezvous at 8 waves/CU exposes more latency than the coarse vmcnt(0)
// drain it removes at this short K (8 K-tiles) with a fat fused epilogue.
// This structure: 2 barriers per 32 MFMA, ~37KB LDS -> 4 blocks/CU = 16
// waves/CU; cross-block wave overlap hides staging latency (m97-mechanism).
//
// s[m,n] = en2[n] - 2 * sum_k zb[m,k]*eb[n,k]  (row-wise argmin target)
// BK=64: row = 8 x 16B blocks; XOR swizzle: block (R,g) at slot R*8 + (g^(R&7))
// -> ds_read_b128 frag reads 2-way (free), global_load_lds stays lane-linear.
// Candidates aggregated in an LDS slab, ONE global atomicAdd per block.
__global__ __launch_bounds__(256, 4)
void k_gemm(const u16* __restrict__ zb, const u16* __restrict__ eb,
            const float* __restrict__ en2, u32* __restrict__ rowMin,
            u32* __restrict__ candCnt, u64* __restrict__ cand) {
    __shared__ __align__(16) u16 As[BM * BK];
    __shared__ __align__(16) u16 Bs[BN * BK];
    __shared__ float en2s[BN];
    __shared__ u32 threshL[BM];
    __shared__ u64 candBuf[LCAP];
    __shared__ u32 ldsCnt, ldsBase;

    const int tid  = threadIdx.x;
    const int lane = tid & 63;
    const int wave = tid >> 6;
    const int rowTile = blockIdx.x * BM;
    const int nTile   = blockIdx.y * BN;
    const int wm = (wave >> 1) * 64;   // wave's row quadrant
    const int wn = (wave & 1) * 64;    // wave's col quadrant

    if (tid < BN) { en2s[tid] = en2[nTile + tid]; threshL[tid] = 0xFFFFFFFFu; }
    if (tid == 0) ldsCnt = 0u;

    // staging: wave w handles wave-issues i = w*4+t (t=0..3) for A and for B.
    // issue i covers rows [i*8, i*8+8); lane l -> row i*8 + (l>>3),
    // k-block g = (l&7) ^ ((l>>3)&7)  (inverse of the XOR swizzle);
    // each 8-lane group covers one full 128B row segment (perfectly coalesced).
    const int srow = (lane >> 3);
    const int sg   = (lane & 7) ^ ((lane >> 3) & 7);
    const u16* gA[4]; const u16* gB[4]; u16* lA[4]; u16* lB[4];
    #pragma unroll
    for (int t = 0; t < 4; t++) {
        int i = wave * 4 + t;
        gA[t] = zb + (size_t)(rowTile + i * 8 + srow) * K_DIM + sg * 8;
        gB[t] = eb + (size_t)(nTile   + i * 8 + srow) * K_DIM + sg * 8;
        lA[t] = As + i * 512;   // 64 blocks * 8 u16 per wave-issue
        lB[t] = Bs + i * 512;
    }

    // fragment read byte offsets (slab 0); slab 1 = offset ^ 64
    int aoff[4], boff[4];
    const int q = lane >> 4;
    #pragma unroll
    for (int t = 0; t < 4; t++) {
        int R  = wm + t * 16 + (lane & 15);
        aoff[t] = (R * 8 + (q ^ (R & 7))) * 16;
        int Rn = wn + t * 16 + (lane & 15);
        boff[t] = (Rn * 8 + (q ^ (Rn & 7))) * 16;
    }

    f32x4 acc[4][4] = {};

    for (int kk = 0; kk < KITERS; kk++) {
        const int ko = kk * BK;
        #pragma unroll
        for (int t = 0; t < 4; t++) {
            ldg_to_lds16(gA[t] + ko, lA[t]);
            ldg_to_lds16(gB[t] + ko, lB[t]);
        }
        __syncthreads();
        short8 af[4], bf_[4];
        #pragma unroll
        for (int t = 0; t < 4; t++) {
            af[t]  = *(const short8*)((const char*)As + aoff[t]);
            bf_[t] = *(const short8*)((const char*)Bs + boff[t]);
        }
        #pragma unroll
        for (int i = 0; i < 4; i++)
            #pragma unroll
            for (int j = 0; j < 4; j++)
                acc[i][j] = __builtin_amdgcn_mfma_f32_16x16x32_bf16(af[i], bf_[j], acc[i][j], 0, 0, 0);
        #pragma unroll
        for (int t = 0; t < 4; t++) {
            af[t]  = *(const short8*)((const char*)As + (aoff[t] ^ 64));
            bf_[t] = *(const short8*)((const char*)Bs + (boff[t] ^ 64));
        }
        #pragma unroll
        for (int i = 0; i < 4; i++)
            #pragma unroll
            for (int j = 0; j < 4; j++)
                acc[i][j] = __builtin_amdgcn_mfma_f32_16x16x32_bf16(af[i], bf_[j], acc[i][j], 0, 0, 0);
        __syncthreads();
    }

    // ---- epilogue: s = en2 - 2*C ; per-row tile min ; candidate capture ----
    float e2v[4];
    #pragma unroll
    for (int j = 0; j < 4; j++) e2v[j] = en2s[wn + j * 16 + (lane & 15)];
    #pragma unroll
    for (int i = 0; i < 4; i++)
        #pragma unroll
        for (int j = 0; j < 4; j++)
            #pragma unroll
            for (int r = 0; r < 4; r++)
                acc[i][j][r] = e2v[j] - 2.0f * acc[i][j][r];

    float rm[4][4];
    #pragma unroll
    for (int i = 0; i < 4; i++)
        #pragma unroll
        for (int r = 0; r < 4; r++)
            rm[i][r] = fminf(fminf(acc[i][0][r], acc[i][1][r]),
                             fminf(acc[i][2][r], acc[i][3][r]));
    #pragma unroll
    for (int d = 1; d < 16; d <<= 1)
        #pragma unroll
        for (int i = 0; i < 4; i++)
            #pragma unroll
            for (int r = 0; r < 4; r++)
                rm[i][r] = fminf(rm[i][r], __shfl_xor(rm[i][r], d));

    if ((lane & 15) == 0) {
        #pragma unroll
        for (int i = 0; i < 4; i++)
            #pragma unroll
            for (int r = 0; r < 4; r++) {
                int lrow = wm + i * 16 + (lane >> 4) * 4 + r;
                u32 o = ford(rm[i][r]);
                atomicMin(&threshL[lrow], o);
                u32 old = atomicMin(&rowMin[rowTile + lrow], o);  // also tightens via earlier tiles
                atomicMin(&threshL[lrow], old);
            }
    }
    __syncthreads();

    #pragma unroll
    for (int i = 0; i < 4; i++) {
        #pragma unroll
        for (int r = 0; r < 4; r++) {
            int lrow = wm + i * 16 + (lane >> 4) * 4 + r;
            float th = fordinv(threshL[lrow]) + TAU2;
            #pragma unroll
            for (int j = 0; j < 4; j++) {
                float sv = acc[i][j][r];
                if (sv <= th) {
                    u32 code = (u32)(nTile + wn + j * 16 + (lane & 15));
                    u64 pk = ((u64)ford(sv) << 32) |
                             (u64)(((u32)(rowTile + lrow) << 13) | code);
                    u32 idx = atomicAdd(&ldsCnt, 1u);       // LDS atomic: cheap
                    if (idx < LCAP) candBuf[idx] = pk;
                    else { u32 g = atomicAdd(candCnt, 1u);  // rare overflow path
                           if (g < CAND_CAP) cand[g] = pk; }
                }
            }
        }
    }
    __syncthreads();
    if (tid == 0) {
        u32 n = ldsCnt < LCAP ? ldsCnt : LCAP;
        ldsBase = atomicAdd(candCnt, n);                    // ONE global atomic per block
    }
    __syncthreads();
    u32 n = ldsCnt < LCAP ? ldsCnt : LCAP;
    for (u32 k2 = tid; k2 < n; k2 += 256) {
        u32 g = ldsBase + k2;
        if (g < CAND_CAP) cand[g] = candBuf[k2];
    }
}

// ---------------- fp32 exact refine of pruned candidates ----------------
// prune vs completed global approx min (+2tau); survivors (~1/row) get an
// exact fp32 512-dot; packed (orderable dist, code) atomicMin -> np tie rule.
__global__ void k_refine(const float* __restrict__ z, const float* __restrict__ emb,
                         const float* __restrict__ en2, const u32* __restrict__ candCnt,
                         const u64* __restrict__ cand, const u32* __restrict__ rowMin,
                         u64* __restrict__ rowBest) {
    u32 cnt = *candCnt; if (cnt > CAND_CAP) cnt = CAND_CAP;
    int gt = blockIdx.x * blockDim.x + threadIdx.x;
    u32 wid = (u32)(gt >> 6);
    int lane = gt & 63;
    u32 nw = (u32)((gridDim.x * blockDim.x) >> 6);
    for (u32 ci = wid; ci < cnt; ci += nw) {
        u64 pk = cand[ci];
        u32 rc = (u32)pk;
        u32 row = rc >> 13, code = rc & (N_CODES - 1);
        float ad = fordinv((u32)(pk >> 32));
        float gm = fordinv(rowMin[row]);
        if (ad > gm + TAU2) continue;   // pruned: can't be the true argmin
        const float4* zp = (const float4*)(z + (size_t)row * K_DIM) + lane * 2;
        const float4* ep = (const float4*)(emb + (size_t)code * K_DIM) + lane * 2;
        float4 a0 = zp[0], a1 = zp[1], b0 = ep[0], b1 = ep[1];
        float d = a0.x*b0.x + a0.y*b0.y + a0.z*b0.z + a0.w*b0.w
                + a1.x*b1.x + a1.y*b1.y + a1.z*b1.z + a1.w*b1.w;
        #pragma unroll
        for (int s = 32; s; s >>= 1) d += __shfl_xor(d, s);
        if (lane == 0) {
            float sv = en2[code] - 2.0f * d;
            u64 bk = ((u64)ford(sv) << 32) | (u64)code;
            atomicMin(rowBest + row, bk);
        }
    }
}

// ---------------- outputs: z_q gather, codes, counts ----------------
__global__ void k_output(const u64* __restrict__ rowBest, const float* __restrict__ emb,
                         float* __restrict__ out, u32* __restrict__ counts) {
    int row = blockIdx.x;
    u64 pk = rowBest[row];
    u32 code = (u32)(pk & 0xFFFFFFFFull);
    int t = threadIdx.x;  // 128 threads, 4 floats each
    float4 v = ((const float4*)(emb + (size_t)code * K_DIM))[t];
    ((float4*)(out + (size_t)row * K_DIM))[t] = v;
    if (t == 0) {
        out[OFF_CODES + row] = (float)code;
        atomicAdd(&counts[code], 1u);
    }
}

// ---------------- loss + perplexity ----------------
__global__ void k_final(const u64* __restrict__ rowBest, const float* __restrict__ zn2,
                        const u32* __restrict__ counts, float* __restrict__ out) {
    __shared__ float red[256];
    int t = threadIdx.x;
    float s1 = 0.f;
    for (int r = t; r < M_ROWS; r += 256)
        s1 += zn2[r] + fordinv((u32)(rowBest[r] >> 32));
    red[t] = s1; __syncthreads();
    for (int w = 128; w; w >>= 1) { if (t < w) red[t] += red[t + w]; __syncthreads(); }
    float lossSum = red[0];
    __syncthreads();
    float s2 = 0.f;
    for (int c = t; c < N_CODES; c += 256) {
        float p = (float)counts[c] * (1.0f / (float)M_ROWS);
        s2 += p * logf(p + 1e-10f);
    }
    red[t] = s2; __syncthreads();
    for (int w = 128; w; w >>= 1) { if (t < w) red[t] += red[t + w]; __syncthreads(); }
    if (t == 0) {
        out[OFF_LOSS] = 0.25f * lossSum / ((float)M_ROWS * (float)K_DIM);
        out[OFF_PERP] = expf(-red[0]);
    }
}

// ---------------- workspace layout (bytes) ----------------
#define WS_ZB      ((size_t)0)                       // 32768*512*2  = 33554432
#define WS_EB      ((size_t)33554432)                // 8192*512*2   = 8388608
#define WS_EN2     ((size_t)41943040)                // 8192*4
#define WS_ZN2     ((size_t)41975808)                // 32768*4
#define WS_ROWMIN  ((size_t)42106880)                // 32768*4
#define WS_ROWBEST ((size_t)42237952)                // 32768*8
#define WS_COUNTS  ((size_t)42500096)                // 8192*4
#define WS_CANDCNT ((size_t)42532864)                // 256
#define WS_CAND    ((size_t)42533120)                // 3M*8 = 25165824 -> total ~67.7MB

extern "C" void kernel_launch(void* const* d_in, const int* in_sizes, int n_in,
                              void* d_out, int out_size, void* d_ws, size_t ws_size,
                              hipStream_t stream) {
    const float* z   = (const float*)d_in[0];
    const float* emb = (const float*)d_in[1];
    float* out = (float*)d_out;
    char* ws = (char*)d_ws;

    u16*  zb      = (u16*)(ws + WS_ZB);
    u16*  eb      = (u16*)(ws + WS_EB);
    float* en2    = (float*)(ws + WS_EN2);
    float* zn2    = (float*)(ws + WS_ZN2);
    u32*  rowMin  = (u32*)(ws + WS_ROWMIN);
    u64*  rowBest = (u64*)(ws + WS_ROWBEST);
    u32*  counts  = (u32*)(ws + WS_COUNTS);
    u32*  candCnt = (u32*)(ws + WS_CANDCNT);
    u64*  cand    = (u64*)(ws + WS_CAND);

    k_init<<<dim3(M_ROWS / 256), dim3(256), 0, stream>>>(rowMin, rowBest, counts, candCnt);
    k_convert<<<dim3(M_ROWS / 4), dim3(256), 0, stream>>>(z, zb, zn2, M_ROWS);
    k_convert<<<dim3(N_CODES / 4), dim3(256), 0, stream>>>(emb, eb, en2, N_CODES);
    k_gemm<<<dim3(M_ROWS / BM, N_CODES / BN), dim3(256), 0, stream>>>(zb, eb, en2, rowMin, candCnt, cand);
    k_refine<<<dim3(1024), dim3(256), 0, stream>>>(z, emb, en2, candCnt, cand, rowMin, rowBest);
    k_output<<<dim3(M_ROWS), dim3(128), 0, stream>>>(rowBest, emb, out, counts);
    k_final<<<dim3(1), dim3(256), 0, stream>>>(rowBest, zn2, counts, out);
}

// Round 7
// 628.618 us; speedup vs baseline: 1.4740x; 1.0304x over previous
//
#include <hip/hip_runtime.h>
#include <stdint.h>
#include <stddef.h>

// Problem constants (fixed by the reference)
#define M_ROWS 32768      // B*N = 16*2048
#define N_CODES 8192
#define K_DIM 512
#define BM 128
#define BN 128
#define BK 64
#define KITERS (K_DIM / BK)     // 8
#define CAND_CAP (3u*1024u*1024u)
#define LCAP 512u               // per-block LDS candidate slab
#define TAU2 2.0f               // 2*tau admission margin for bf16 approx distances (>10 sigma)

// Output layout (floats): z_q [0,16777216), codes [16777216,16809984), loss, perp
#define OFF_CODES 16777216
#define OFF_LOSS  (16777216 + 32768)
#define OFF_PERP  (16777216 + 32768 + 1)

using short8  = __attribute__((ext_vector_type(8))) short;
using ushort8 = __attribute__((ext_vector_type(8))) unsigned short;
using f32x4   = __attribute__((ext_vector_type(4))) float;

typedef unsigned short u16;
typedef unsigned int   u32;
typedef unsigned long long u64;

// ---- orderable-uint encoding of float (monotone: uint min == float min) ----
__device__ __forceinline__ u32 ford(float f) {
    u32 u = __float_as_uint(f);
    return (u & 0x80000000u) ? ~u : (u | 0x80000000u);
}
__device__ __forceinline__ float fordinv(u32 u) {
    u32 v = (u & 0x80000000u) ? (u & 0x7FFFFFFFu) : ~u;
    return __uint_as_float(v);
}
// fp32 -> bf16 (RNE)
__device__ __forceinline__ u16 f2bf(float f) {
    u32 u = __float_as_uint(f);
    u = u + 0x7FFFu + ((u >> 16) & 1u);
    return (u16)(u >> 16);
}

// async global->LDS, 16B per lane; LDS dest = wave-uniform base + lane*16
__device__ __forceinline__ void ldg_to_lds16(const u16* g, u16* l) {
    __builtin_amdgcn_global_load_lds((__attribute__((address_space(1))) void*)(g),
                                     (__attribute__((address_space(3))) void*)(l),
                                     16, 0, 0);
}

// ------------- fp32 -> bf16 convert + row squared norms (+ fused init) -------------
// The z-call (first launch) also performs all scratch init (saves the k_init launch):
// grid 8192x256 = 2.1M threads covers M_ROWS/N_CODES index ranges.
__global__ void k_convert(const float* __restrict__ src, u16* __restrict__ dst,
                          float* __restrict__ nrm2, int nrows,
                          u32* rowMin, u64* rowBest, u32* counts, u32* candCnt,
                          float* fsum, u32* ticket) {
    if (rowMin) {
        int g = blockIdx.x * blockDim.x + threadIdx.x;
        if (g < M_ROWS) { rowMin[g] = 0xFFFFFFFFu; rowBest[g] = ~0ull; }
        if (g < N_CODES) counts[g] = 0u;
        if (g == 0) { *candCnt = 0u; *fsum = 0.f; *ticket = 0u; }
    }
    int row  = blockIdx.x * 4 + (threadIdx.x >> 6);
    int lane = threadIdx.x & 63;
    if (row >= nrows) return;
    const float* p = src + (size_t)row * K_DIM + lane * 8;
    float4 a = *(const float4*)p;
    float4 b = *(const float4*)(p + 4);
    ushort8 v;
    v[0]=f2bf(a.x); v[1]=f2bf(a.y); v[2]=f2bf(a.z); v[3]=f2bf(a.w);
    v[4]=f2bf(b.x); v[5]=f2bf(b.y); v[6]=f2bf(b.z); v[7]=f2bf(b.w);
    *(ushort8*)(dst + (size_t)row * K_DIM + lane * 8) = v;
    float ss = a.x*a.x + a.y*a.y + a.z*a.z + a.w*a.w
             + b.x*b.x + b.y*b.y + b.z*b.z + b.w*b.w;
    #pragma unroll
    for (int s = 32; s; s >>= 1) ss += __shfl_xor(ss, s);
    if (lane == 0) nrm2[row] = ss;
}

// ---------------- main bf16 GEMM + fused min/candidate epilogue ----------------
// PROVEN baseline structure (R6: 423us, MfmaUtil 29%, Occ 41% = 4 blocks/CU).
// Coarse 2-barriers-per-K-step + 16 waves/CU cross-block overlap beats all
// fine-grained phase pipelines at this short K (R2-R5 evidence). DO NOT
// re-pipeline without first beating 423us in isolation.
__global__ __launch_bounds__(256, 4)
void k_gemm(const u16* __restrict__ zb, const u16* __restrict__ eb,
            const float* __restrict__ en2, u32* __restrict__ rowMin,
            u32* __restrict__ candCnt, u64* __restrict__ cand) {
    __shared__ __align__(16) u16 As[BM * BK];
    __shared__ __align__(16) u16 Bs[BN * BK];
    __shared__ float en2s[BN];
    __shared__ u32 threshL[BM];
    __shared__ u64 candBuf[LCAP];
    __shared__ u32 ldsCnt, ldsBase;

    const int tid  = threadIdx.x;
    const int lane = tid & 63;
    const int wave = tid >> 6;
    const int rowTile = blockIdx.x * BM;
    const int nTile   = blockIdx.y * BN;
    const int wm = (wave >> 1) * 64;   // wave's row quadrant
    const int wn = (wave & 1) * 64;    // wave's col quadrant

    if (tid < BN) { en2s[tid] = en2[nTile + tid]; threshL[tid] = 0xFFFFFFFFu; }
    if (tid == 0) ldsCnt = 0u;

    // staging: wave w handles wave-issues i = w*4+t (t=0..3) for A and for B.
    // issue i covers rows [i*8, i*8+8); lane l -> row i*8 + (l>>3),
    // k-block g = (l&7) ^ ((l>>3)&7)  (inverse of the XOR swizzle);
    // each 8-lane group covers one full 128B row segment (perfectly coalesced).
    const int srow = (lane >> 3);
    const int sg   = (lane & 7) ^ ((lane >> 3) & 7);
    const u16* gA[4]; const u16* gB[4]; u16* lA[4]; u16* lB[4];
    #pragma unroll
    for (int t = 0; t < 4; t++) {
        int i = wave * 4 + t;
        gA[t] = zb + (size_t)(rowTile + i * 8 + srow) * K_DIM + sg * 8;
        gB[t] = eb + (size_t)(nTile   + i * 8 + srow) * K_DIM + sg * 8;
        lA[t] = As + i * 512;   // 64 blocks * 8 u16 per wave-issue
        lB[t] = Bs + i * 512;
    }

    // fragment read byte offsets (slab 0); slab 1 = offset ^ 64
    int aoff[4], boff[4];
    const int q = lane >> 4;
    #pragma unroll
    for (int t = 0; t < 4; t++) {
        int R  = wm + t * 16 + (lane & 15);
        aoff[t] = (R * 8 + (q ^ (R & 7))) * 16;
        int Rn = wn + t * 16 + (lane & 15);
        boff[t] = (Rn * 8 + (q ^ (Rn & 7))) * 16;
    }

    f32x4 acc[4][4] = {};

    for (int kk = 0; kk < KITERS; kk++) {
        const int ko = kk * BK;
        #pragma unroll
        for (int t = 0; t < 4; t++) {
            ldg_to_lds16(gA[t] + ko, lA[t]);
            ldg_to_lds16(gB[t] + ko, lB[t]);
        }
        __syncthreads();
        short8 af[4], bf_[4];
        #pragma unroll
        for (int t = 0; t < 4; t++) {
            af[t]  = *(const short8*)((const char*)As + aoff[t]);
            bf_[t] = *(const short8*)((const char*)Bs + boff[t]);
        }
        #pragma unroll
        for (int i = 0; i < 4; i++)
            #pragma unroll
            for (int j = 0; j < 4; j++)
                acc[i][j] = __builtin_amdgcn_mfma_f32_16x16x32_bf16(af[i], bf_[j], acc[i][j], 0, 0, 0);
        #pragma unroll
        for (int t = 0; t < 4; t++) {
            af[t]  = *(const short8*)((const char*)As + (aoff[t] ^ 64));
            bf_[t] = *(const short8*)((const char*)Bs + (boff[t] ^ 64));
        }
        #pragma unroll
        for (int i = 0; i < 4; i++)
            #pragma unroll
            for (int j = 0; j < 4; j++)
                acc[i][j] = __builtin_amdgcn_mfma_f32_16x16x32_bf16(af[i], bf_[j], acc[i][j], 0, 0, 0);
        __syncthreads();
    }

    // ---- epilogue: s = en2 - 2*C ; per-row tile min ; candidate capture ----
    float e2v[4];
    #pragma unroll
    for (int j = 0; j < 4; j++) e2v[j] = en2s[wn + j * 16 + (lane & 15)];
    #pragma unroll
    for (int i = 0; i < 4; i++)
        #pragma unroll
        for (int j = 0; j < 4; j++)
            #pragma unroll
            for (int r = 0; r < 4; r++)
                acc[i][j][r] = e2v[j] - 2.0f * acc[i][j][r];

    float rm[4][4];
    #pragma unroll
    for (int i = 0; i < 4; i++)
        #pragma unroll
        for (int r = 0; r < 4; r++)
            rm[i][r] = fminf(fminf(acc[i][0][r], acc[i][1][r]),
                             fminf(acc[i][2][r], acc[i][3][r]));
    #pragma unroll
    for (int d = 1; d < 16; d <<= 1)
        #pragma unroll
        for (int i = 0; i < 4; i++)
            #pragma unroll
            for (int r = 0; r < 4; r++)
                rm[i][r] = fminf(rm[i][r], __shfl_xor(rm[i][r], d));

    if ((lane & 15) == 0) {
        #pragma unroll
        for (int i = 0; i < 4; i++)
            #pragma unroll
            for (int r = 0; r < 4; r++) {
                int lrow = wm + i * 16 + (lane >> 4) * 4 + r;
                u32 o = ford(rm[i][r]);
                atomicMin(&threshL[lrow], o);
                u32 old = atomicMin(&rowMin[rowTile + lrow], o);  // also tightens via earlier tiles
                atomicMin(&threshL[lrow], old);
            }
    }
    __syncthreads();

    #pragma unroll
    for (int i = 0; i < 4; i++) {
        #pragma unroll
        for (int r = 0; r < 4; r++) {
            int lrow = wm + i * 16 + (lane >> 4) * 4 + r;
            float th = fordinv(threshL[lrow]) + TAU2;
            #pragma unroll
            for (int j = 0; j < 4; j++) {
                float sv = acc[i][j][r];
                if (sv <= th) {
                    u32 code = (u32)(nTile + wn + j * 16 + (lane & 15));
                    u64 pk = ((u64)ford(sv) << 32) |
                             (u64)(((u32)(rowTile + lrow) << 13) | code);
                    u32 idx = atomicAdd(&ldsCnt, 1u);       // LDS atomic: cheap
                    if (idx < LCAP) candBuf[idx] = pk;
                    else { u32 g = atomicAdd(candCnt, 1u);  // rare overflow path
                           if (g < CAND_CAP) cand[g] = pk; }
                }
            }
        }
    }
    __syncthreads();
    if (tid == 0) {
        u32 n = ldsCnt < LCAP ? ldsCnt : LCAP;
        ldsBase = atomicAdd(candCnt, n);                    // ONE global atomic per block
    }
    __syncthreads();
    u32 n = ldsCnt < LCAP ? ldsCnt : LCAP;
    for (u32 k2 = tid; k2 < n; k2 += 256) {
        u32 g = ldsBase + k2;
        if (g < CAND_CAP) cand[g] = candBuf[k2];
    }
}

// ---------------- fp32 exact refine of pruned candidates ----------------
// R7: wave-parallel scan. Each wave loads 64 candidates coalesced (one/lane),
// prunes vs global min (+2tau) in parallel, ballots, then the FULL wave does
// the exact fp32 512-dot for each survivor (~1% of candidates). Replaces the
// serial 1-candidate-per-wave latency chain (~8.4M broadcast loads).
__global__ void k_refine(const float* __restrict__ z, const float* __restrict__ emb,
                         const float* __restrict__ en2, const u32* __restrict__ candCnt,
                         const u64* __restrict__ cand, const u32* __restrict__ rowMin,
                         u64* __restrict__ rowBest) {
    u32 cnt = *candCnt; if (cnt > CAND_CAP) cnt = CAND_CAP;
    int gt = blockIdx.x * blockDim.x + threadIdx.x;
    u32 wid = (u32)(gt >> 6);
    int lane = gt & 63;
    u32 nw = (u32)((gridDim.x * blockDim.x) >> 6);
    for (u32 base = wid * 64u; base < cnt; base += nw * 64u) {
        u32 ci = base + (u32)lane;
        u32 row = 0, code = 0;
        bool live = false;
        if (ci < cnt) {
            u64 pk = cand[ci];
            u32 rc = (u32)pk;
            row = rc >> 13; code = rc & (N_CODES - 1);
            float ad = fordinv((u32)(pk >> 32));
            float gm = fordinv(rowMin[row]);
            live = (ad <= gm + TAU2);
        }
        u64 mask = __ballot(live);
        while (mask) {
            int s = (int)(__ffsll((long long)mask) - 1);
            mask &= mask - 1;
            u32 srow  = __shfl(row,  s);
            u32 scode = __shfl(code, s);
            const float4* zp = (const float4*)(z + (size_t)srow * K_DIM) + lane * 2;
            const float4* ep = (const float4*)(emb + (size_t)scode * K_DIM) + lane * 2;
            float4 a0 = zp[0], a1 = zp[1], b0 = ep[0], b1 = ep[1];
            float d = a0.x*b0.x + a0.y*b0.y + a0.z*b0.z + a0.w*b0.w
                    + a1.x*b1.x + a1.y*b1.y + a1.z*b1.z + a1.w*b1.w;
            #pragma unroll
            for (int sh = 32; sh; sh >>= 1) d += __shfl_xor(d, sh);
            if (lane == 0) {
                float sv = en2[scode] - 2.0f * d;
                u64 bk = ((u64)ford(sv) << 32) | (u64)scode;
                atomicMin(rowBest + srow, bk);
            }
        }
    }
}

// ---------------- outputs: z_q gather, codes, counts ----------------
// R7: 4 rows per block (fewer dispatch units, same coalescing).
__global__ void k_output(const u64* __restrict__ rowBest, const float* __restrict__ emb,
                         float* __restrict__ out, u32* __restrict__ counts) {
    int row = blockIdx.x * 4 + (threadIdx.x >> 7);
    int t   = threadIdx.x & 127;   // 128 threads/row, 4 floats each
    u64 pk = rowBest[row];
    u32 code = (u32)(pk & 0xFFFFFFFFull);
    float4 v = ((const float4*)(emb + (size_t)code * K_DIM))[t];
    ((float4*)(out + (size_t)row * K_DIM))[t] = v;
    if (t == 0) {
        out[OFF_CODES + row] = (float)code;
        atomicAdd(&counts[code], 1u);
    }
}

// ---------------- loss + perplexity ----------------
// R7: 32-block partial sums + ticket; last block reads the device-scope sum
// via atomicAdd(fsum, 0) and computes the 8192-entry entropy + final scalars.
__global__ void k_final(const u64* __restrict__ rowBest, const float* __restrict__ zn2,
                        const u32* __restrict__ counts, float* __restrict__ out,
                        float* __restrict__ fsum, u32* __restrict__ ticket) {
    __shared__ float red[256];
    __shared__ int lastBlk;
    __shared__ float lossSumSh;
    int t = threadIdx.x;
    float s1 = 0.f;
    for (int r = blockIdx.x * 256 + t; r < M_ROWS; r += gridDim.x * 256)
        s1 += zn2[r] + fordinv((u32)(rowBest[r] >> 32));
    red[t] = s1; __syncthreads();
    for (int w = 128; w; w >>= 1) { if (t < w) red[t] += red[t + w]; __syncthreads(); }
    if (t == 0) {
        atomicAdd(fsum, red[0]);
        __threadfence();
        lastBlk = (atomicAdd(ticket, 1u) == gridDim.x - 1) ? 1 : 0;
    }
    __syncthreads();
    if (!lastBlk) return;
    if (t == 0) lossSumSh = atomicAdd(fsum, 0.0f);   // device-scope read of total
    float s2 = 0.f;
    for (int c = t; c < N_CODES; c += 256) {
        float p = (float)counts[c] * (1.0f / (float)M_ROWS);
        s2 += p * logf(p + 1e-10f);
    }
    red[t] = s2; __syncthreads();
    for (int w = 128; w; w >>= 1) { if (t < w) red[t] += red[t + w]; __syncthreads(); }
    if (t == 0) {
        out[OFF_LOSS] = 0.25f * lossSumSh / ((float)M_ROWS * (float)K_DIM);
        out[OFF_PERP] = expf(-red[0]);
    }
}

// ---------------- workspace layout (bytes) ----------------
#define WS_ZB      ((size_t)0)                       // 32768*512*2  = 33554432
#define WS_EB      ((size_t)33554432)                // 8192*512*2   = 8388608
#define WS_EN2     ((size_t)41943040)                // 8192*4
#define WS_ZN2     ((size_t)41975808)                // 32768*4
#define WS_ROWMIN  ((size_t)42106880)                // 32768*4
#define WS_ROWBEST ((size_t)42237952)                // 32768*8
#define WS_COUNTS  ((size_t)42500096)                // 8192*4
#define WS_CANDCNT ((size_t)42532864)                // candCnt @+0, fsum @+8, ticket @+12
#define WS_CAND    ((size_t)42533120)                // 3M*8 = 25165824 -> total ~67.7MB

extern "C" void kernel_launch(void* const* d_in, const int* in_sizes, int n_in,
                              void* d_out, int out_size, void* d_ws, size_t ws_size,
                              hipStream_t stream) {
    const float* z   = (const float*)d_in[0];
    const float* emb = (const float*)d_in[1];
    float* out = (float*)d_out;
    char* ws = (char*)d_ws;

    u16*  zb      = (u16*)(ws + WS_ZB);
    u16*  eb      = (u16*)(ws + WS_EB);
    float* en2    = (float*)(ws + WS_EN2);
    float* zn2    = (float*)(ws + WS_ZN2);
    u32*  rowMin  = (u32*)(ws + WS_ROWMIN);
    u64*  rowBest = (u64*)(ws + WS_ROWBEST);
    u32*  counts  = (u32*)(ws + WS_COUNTS);
    u32*  candCnt = (u32*)(ws + WS_CANDCNT);
    float* fsum   = (float*)(ws + WS_CANDCNT + 8);
    u32*  ticket  = (u32*)(ws + WS_CANDCNT + 12);
    u64*  cand    = (u64*)(ws + WS_CAND);

    // z-convert also performs all scratch init (grid covers all init ranges)
    k_convert<<<dim3(M_ROWS / 4), dim3(256), 0, stream>>>(z, zb, zn2, M_ROWS,
                                                          rowMin, rowBest, counts, candCnt, fsum, ticket);
    k_convert<<<dim3(N_CODES / 4), dim3(256), 0, stream>>>(emb, eb, en2, N_CODES,
                                                           nullptr, nullptr, nullptr, nullptr, nullptr, nullptr);
    k_gemm<<<dim3(M_ROWS / BM, N_CODES / BN), dim3(256), 0, stream>>>(zb, eb, en2, rowMin, candCnt, cand);
    k_refine<<<dim3(1024), dim3(256), 0, stream>>>(z, emb, en2, candCnt, cand, rowMin, rowBest);
    k_output<<<dim3(M_ROWS / 4), dim3(512), 0, stream>>>(rowBest, emb, out, counts);
    k_final<<<dim3(32), dim3(256), 0, stream>>>(rowBest, zn2, counts, out, fsum, ticket);
}